// Round 1
// baseline (128.306 us; speedup 1.0000x reference)
//
#include <hip/hip_runtime.h>

typedef __attribute__((ext_vector_type(8))) short short8;
typedef __attribute__((ext_vector_type(4))) float floatx4;

#define B_    8
#define CIN   256
#define NSP   2048   // T*H*W = 8*16*16
#define FF    512
#define COUT  256
#define NTOT  (B_*COUT*NSP)

__device__ __forceinline__ unsigned short f2bf(float f) {
  unsigned int u = __float_as_uint(f);
  u += 0x7fffu + ((u >> 16) & 1u);   // RNE
  return (unsigned short)(u >> 16);
}

// ---------------------------------------------------------------------------
// K1: blocks 0..31  -> M = Wout @ Wv  (bf16, 8 rows per block)
//     blocks 32..1055 -> transpose x[b][c][n] (f32) -> XT[b][n][c] (bf16)
//     block 0 also zeros the stats accumulators.
// ---------------------------------------------------------------------------
__global__ __launch_bounds__(256) void k1_prep(
    const float* __restrict__ x, const float* __restrict__ Wv,
    const float* __restrict__ Wout,
    unsigned short* __restrict__ Mb, unsigned short* __restrict__ XT,
    float* __restrict__ stats)
{
  __shared__ float lds[64 * 65];
  const int tid = threadIdx.x;
  const int bx  = blockIdx.x;

  if (bx < 32) {
    if (bx == 0) { stats[tid] = 0.f; stats[256 + tid] = 0.f; }
    const int rbase = bx * 8;
    // stage 8 rows of Wout (8 x 512 f32) into LDS
    #pragma unroll
    for (int i = 0; i < 16; ++i) {
      int idx = i * 256 + tid;
      lds[idx] = Wout[(size_t)rbase * 512 + idx];
    }
    __syncthreads();
    float acc[8] = {0.f,0.f,0.f,0.f,0.f,0.f,0.f,0.f};
    #pragma unroll 8
    for (int f = 0; f < 512; ++f) {
      float w = Wv[(size_t)f * 256 + tid];   // coalesced, L2-hot
      #pragma unroll
      for (int j = 0; j < 8; ++j) acc[j] += lds[j * 512 + f] * w;  // LDS broadcast
    }
    #pragma unroll
    for (int j = 0; j < 8; ++j)
      Mb[(size_t)(rbase + j) * 256 + tid] = f2bf(acc[j]);
  } else {
    const int idx = bx - 32;             // 0..1023
    const int b   = idx >> 7;            // 8 batches
    const int rem = idx & 127;           // 32 n-tiles * 4 c-tiles
    const int n0  = (rem & 31) * 64;
    const int c0  = (rem >> 5) * 64;
    const float* xb = x + (size_t)b * CIN * NSP;
    const int n_l = tid & 63;
    const int c_l0 = tid >> 6;
    #pragma unroll
    for (int p = 0; p < 16; ++p) {
      int c_l = c_l0 + p * 4;
      lds[c_l * 65 + n_l] = xb[(size_t)(c0 + c_l) * NSP + n0 + n_l];
    }
    __syncthreads();
    const int cp   = tid & 31;   // c pair index
    const int n_l2 = tid >> 5;   // 8 n rows per pass
    unsigned int* XT32 = (unsigned int*)XT;
    #pragma unroll
    for (int p = 0; p < 8; ++p) {
      int nn = n_l2 + p * 8;
      unsigned short lo = f2bf(lds[(2 * cp)     * 65 + nn]);
      unsigned short hi = f2bf(lds[(2 * cp + 1) * 65 + nn]);
      XT32[((size_t)b * NSP + n0 + nn) * 128 + (c0 >> 1) + cp] =
          (unsigned int)lo | ((unsigned int)hi << 16);
    }
  }
}

// ---------------------------------------------------------------------------
// K2: o = M @ x  (bf16 MFMA, A/B fragments straight from L2-cached global),
//     fused bias+relu+residual, bf16 y write, BN partial sums.
// grid (16 n-blocks, 2 oc-blocks, 8 batches); 256 thr = 4 waves, each 64x64.
// ---------------------------------------------------------------------------
__global__ __launch_bounds__(256) void k2_gemm(
    const float* __restrict__ x, const unsigned short* __restrict__ Mb,
    const unsigned short* __restrict__ XT, const float* __restrict__ bout,
    unsigned short* __restrict__ ybf, float* __restrict__ stats)
{
  __shared__ float ls[128], lq[128];
  const int tid  = threadIdx.x;
  const int lane = tid & 63;
  const int wave = tid >> 6;
  const int b    = blockIdx.z;
  const int ocb  = blockIdx.y * 128;
  const int nb   = blockIdx.x * 128;
  const int wocb = ocb + (wave & 1) * 64;
  const int wnb  = nb + (wave >> 1) * 64;
  const int m16  = lane & 15;
  const int q    = lane >> 4;

  if (tid < 128) { ls[tid] = 0.f; lq[tid] = 0.f; }

  floatx4 acc[4][4];
  #pragma unroll
  for (int i = 0; i < 4; ++i)
    #pragma unroll
    for (int j = 0; j < 4; ++j)
      acc[i][j] = (floatx4){0.f, 0.f, 0.f, 0.f};

  // A fragment: lane reads M[wocb+ti*16+m16][kk*32 + q*8 .. +7] (16B contiguous)
  // B fragment: lane reads XT[b][wnb+tj*16+m16][kk*32 + q*8 .. +7]
  const unsigned short* Abase = Mb + (size_t)(wocb + m16) * 256 + q * 8;
  const unsigned short* Bbase = XT + ((size_t)b * NSP + wnb + m16) * 256 + q * 8;

  #pragma unroll
  for (int kk = 0; kk < 8; ++kk) {
    short8 av[4], bv[4];
    #pragma unroll
    for (int t = 0; t < 4; ++t) {
      av[t] = *(const short8*)(Abase + (size_t)t * 16 * 256 + kk * 32);
      bv[t] = *(const short8*)(Bbase + (size_t)t * 16 * 256 + kk * 32);
    }
    #pragma unroll
    for (int i = 0; i < 4; ++i)
      #pragma unroll
      for (int j = 0; j < 4; ++j)
        acc[i][j] = __builtin_amdgcn_mfma_f32_16x16x32_bf16(av[i], bv[j], acc[i][j], 0, 0, 0);
  }

  __syncthreads();  // ls/lq zeros visible

  // D layout: col(n) = lane&15, row(oc) = q*4 + reg
  #pragma unroll
  for (int ti = 0; ti < 4; ++ti) {
    #pragma unroll
    for (int r = 0; r < 4; ++r) {
      const int oc = wocb + ti * 16 + q * 4 + r;
      const float bo = bout[oc];
      float s = 0.f, s2 = 0.f;
      #pragma unroll
      for (int tj = 0; tj < 4; ++tj) {
        const int n = wnb + tj * 16 + m16;
        float o = acc[ti][tj][r] + bo;
        o = fmaxf(o, 0.f);
        const size_t gidx = ((size_t)(b * COUT + oc)) * NSP + n;
        float y = x[gidx] + o;
        ybf[gidx] = f2bf(y);
        s += y;
        s2 += y * y;
      }
      // reduce over the 16 n-lanes (stays within quad for masks < 16)
      #pragma unroll
      for (int d = 1; d < 16; d <<= 1) {
        s  += __shfl_xor(s, d, 64);
        s2 += __shfl_xor(s2, d, 64);
      }
      if (m16 == 0) {
        atomicAdd(&ls[oc - ocb], s);
        atomicAdd(&lq[oc - ocb], s2);
      }
    }
  }
  __syncthreads();
  if (tid < 128) {
    atomicAdd(&stats[ocb + tid], ls[tid]);
    atomicAdd(&stats[256 + ocb + tid], lq[tid]);
  }
}

// ---------------------------------------------------------------------------
// K3: finalize per-channel scale/shift
// ---------------------------------------------------------------------------
__global__ void k3_finalize(const float* __restrict__ stats,
                            const float* __restrict__ gamma,
                            const float* __restrict__ beta,
                            float* __restrict__ scsh)
{
  const int c = threadIdx.x;
  const float inv_n = 1.f / 16384.f;
  float m = stats[c] * inv_n;
  float v = stats[256 + c] * inv_n - m * m;
  float inv = rsqrtf(v + 1e-5f);
  float sc = gamma[c] * inv;
  scsh[c] = sc;
  scsh[256 + c] = beta[c] - m * sc;
}

// ---------------------------------------------------------------------------
// K4: out = y * scale[c] + shift[c]   (8 bf16 per thread, fully coalesced)
// ---------------------------------------------------------------------------
__global__ __launch_bounds__(256) void k4_norm(
    const unsigned short* __restrict__ ybf, const float* __restrict__ scsh,
    float* __restrict__ out)
{
  const size_t i = ((size_t)blockIdx.x * 256 + threadIdx.x) * 8;
  const int c = (int)((i >> 11) & 255);
  const float sc = scsh[c], sh = scsh[256 + c];
  const uint4 raw = *(const uint4*)(ybf + i);
  float4 o0, o1;
  o0.x = __uint_as_float(raw.x << 16)         * sc + sh;
  o0.y = __uint_as_float(raw.x & 0xffff0000u) * sc + sh;
  o0.z = __uint_as_float(raw.y << 16)         * sc + sh;
  o0.w = __uint_as_float(raw.y & 0xffff0000u) * sc + sh;
  o1.x = __uint_as_float(raw.z << 16)         * sc + sh;
  o1.y = __uint_as_float(raw.z & 0xffff0000u) * sc + sh;
  o1.z = __uint_as_float(raw.w << 16)         * sc + sh;
  o1.w = __uint_as_float(raw.w & 0xffff0000u) * sc + sh;
  *(float4*)(out + i)     = o0;
  *(float4*)(out + i + 4) = o1;
}

extern "C" void kernel_launch(void* const* d_in, const int* in_sizes, int n_in,
                              void* d_out, int out_size, void* d_ws, size_t ws_size,
                              hipStream_t stream) {
  const float* x     = (const float*)d_in[0];
  // d_in[1] = Wk, d_in[2] = Wq : mathematically dead (softmax rows sum to 1)
  const float* Wv    = (const float*)d_in[3];
  const float* Wout  = (const float*)d_in[4];
  const float* bout  = (const float*)d_in[5];
  const float* gamma = (const float*)d_in[6];
  const float* beta  = (const float*)d_in[7];
  float* out = (float*)d_out;

  char* w = (char*)d_ws;
  unsigned short* Mb = (unsigned short*)w;                         // 128 KiB
  unsigned short* XT = (unsigned short*)(w + 131072);              // 8 MiB
  unsigned short* yb = (unsigned short*)(w + 131072 + 8388608);    // 8 MiB
  float* stats = (float*)(w + 131072 + 8388608 + 8388608);         // 512 f32
  float* scsh  = stats + 512;                                      // 512 f32

  hipLaunchKernelGGL(k1_prep, dim3(32 + 1024), dim3(256), 0, stream,
                     x, Wv, Wout, Mb, XT, stats);
  hipLaunchKernelGGL(k2_gemm, dim3(16, 2, 8), dim3(256), 0, stream,
                     x, Mb, XT, bout, yb, stats);
  hipLaunchKernelGGL(k3_finalize, dim3(1), dim3(256), 0, stream,
                     stats, gamma, beta, scsh);
  hipLaunchKernelGGL(k4_norm, dim3(NTOT / (256 * 8)), dim3(256), 0, stream,
                     yb, scsh, out);
}